// Round 9
// baseline (340.259 us; speedup 1.0000x reference)
//
#include <hip/hip_runtime.h>
#include <hip/hip_bf16.h>

typedef __attribute__((ext_vector_type(8))) short short8;
typedef __attribute__((ext_vector_type(4))) float f32x4;

#define N_NODES 5000
#define E_EDGES 16000
#define B_Q 8
#define D_DIM 128

// ---- ws layout (float offsets) ----
#define OFF_U     0            // bf16  8,192,000 (gemm1 -> mega)
#define OFF_G     4096000      // bf16 16,384,000 (mega -> segsm)
#define OFF_HN    12288000     // f32 640,000
#define OFF_WDST  12928000     // f32 640,000
#define OFF_VB    13568000     // f32 4,096
#define OFF_W1T   13572096     // bf16 65,536
#define OFF_W2T   13604864     // bf16 131,072
#define OFF_W3T   13670400     // bf16 32,768
#define OFF_WALLT 13686784     // bf16 98,304
#define OFF_CNT   13735936     // int 5,000
#define OFF_ROWP  13740936     // int 5,001
#define OFF_CUR   13745937     // int 5,000
#define OFF_ECSR  13750937     // int 16,000
#define OFF_HSRC  13766944     // bf16 2,048,000 (16B aligned)
#define OFF_HREL  14790944     // bf16 2,048,000
// end = 15,814,944 floats = 63.3 MB

__device__ __forceinline__ float leaky(float x) { return x > 0.f ? x : 0.01f * x; }
__device__ __forceinline__ int sgnk(int a, int b) { int d = a - b; return d > 0 ? 2 : (d == 0 ? 1 : 0); }
__device__ __forceinline__ unsigned short f2bf(float f) {
    __hip_bfloat16 h = __float2bfloat16(f);
    unsigned short r; __builtin_memcpy(&r, &h, 2); return r;
}
__device__ __forceinline__ unsigned pk2(float a, float b) {
    return (unsigned)f2bf(a) | ((unsigned)f2bf(b) << 16);
}
__device__ __forceinline__ float bflo(unsigned w) { return __uint_as_float(w << 16); }
__device__ __forceinline__ float bfhi(unsigned w) { return __uint_as_float(w & 0xffff0000u); }
__device__ __forceinline__ float bf2f(unsigned short s) { return __uint_as_float(((unsigned)s) << 16); }
__device__ __forceinline__ unsigned addpk(unsigned a, unsigned b) {
    return pk2(bflo(a) + bflo(b), bfhi(a) + bfhi(b));
}

// XOR swizzles: byte ^= (row&7)<<4, row strides 128/256/512 B
#define SWZB(row, lb)  (((row) << 7) + ((lb) ^ (((row) & 7) << 4)))
#define SWZ256(row, lb) (((row) << 8) + ((lb) ^ (((row) & 7) << 4)))
#define SWZ512(row, lb) (((row) << 9) + ((lb) ^ (((row) & 7) << 4)))

// ---------------- prep kernels ----------------
__global__ void k_wprep(const float* __restrict__ W1, const float* __restrict__ W2,
                        const float* __restrict__ W3, const float* __restrict__ Wss,
                        const float* __restrict__ Wee,
                        ushort* __restrict__ W1t, ushort* __restrict__ W2t,
                        ushort* __restrict__ W3t, ushort* __restrict__ Wallt) {
    int tid = blockIdx.x * 256 + threadIdx.x;
    if (tid < 131072) {                       // W2t[n][k] = W2[k][n], 256x512
        int n = tid >> 9, k = tid & 511;
        W2t[tid] = f2bf(W2[k * 256 + n]);
    } else if (tid < 163840) {                // W3t[n][k] = W3[k][n], 128x256
        int q = tid - 131072; int n = q >> 8, k = q & 255;
        W3t[q] = f2bf(W3[k * 128 + n]);
    } else if (tid < 262144) {                // Wallt[c][n][k], c = {ss0..2, ee0..2}
        int q = tid - 163840; int c = q >> 14, rr = q & 16383, n = rr >> 7, k = rr & 127;
        const float* Wm = (c < 3) ? Wss : Wee; int cc = (c < 3) ? c : c - 3;
        Wallt[q] = f2bf(Wm[cc * 16384 + k * 128 + n]);
    } else if (tid < 327680) {                // W1t[n][k] = W1[k][n], 512x128 (top half)
        int q = tid - 262144; int n = q >> 7, k = q & 127;
        W1t[q] = f2bf(W1[k * 512 + n]);
    }
}

__global__ void k_node(const int* __restrict__ node_idx, const float* __restrict__ node_time,
                       const float* __restrict__ syn, const float* __restrict__ diae,
                       const float* __restrict__ diaw, const float* __restrict__ diab,
                       const float* __restrict__ attn_i, const float* __restrict__ attn_j,
                       float* __restrict__ h_n, float* __restrict__ w_dst) {
    int n = blockIdx.x, d = threadIdx.x;
    int nid = node_idx[n];
    float h = syn[nid * D_DIM + d];
    if (d >= 64) {
        int q = d - 64;
        h += diae[nid * 64 + q] * sinf(diaw[nid * 64 + q] * node_time[n] + diab[nid * 64 + q]);
    }
    h_n[n * D_DIM + d] = h;
    w_dst[n * D_DIM + d] = h * attn_i[d] * attn_j[d];
}

__global__ void k_vb(const float* __restrict__ bt2v, const float* __restrict__ W1,
                     const float* __restrict__ b1, float* __restrict__ v_b) {
    int b = blockIdx.x, j = threadIdx.x;
    float acc = b1[j];
    for (int i = 0; i < 128; ++i)
        acc = fmaf(bt2v[b * 128 + i], W1[(128 + i) * 512 + j], acc);
    v_b[b * 512 + j] = acc;
}

// per-edge gather tables: hsrc[e][d] = h_n[src[e]][d], hrel[e][d] = rel_embed[rtyp[e]][d]
__global__ void k_egather(const int* __restrict__ src, const int* __restrict__ rtyp,
                          const float* __restrict__ h_n, const float* __restrict__ rel_embed,
                          ushort* __restrict__ hsrc, ushort* __restrict__ hrel) {
    int idx = blockIdx.x * 256 + threadIdx.x;  // e*128 + d
    int e = idx >> 7, d = idx & 127;
    hsrc[idx] = f2bf(h_n[src[e] * 128 + d]);
    hrel[idx] = f2bf(rel_embed[rtyp[e] * 128 + d]);
}

// ---------------- CSR build ----------------
__global__ void k_count(const int* __restrict__ dst, int* __restrict__ cnt) {
    int e = blockIdx.x * 256 + threadIdx.x;
    if (e < E_EDGES) atomicAdd(&cnt[dst[e]], 1);
}

__global__ void k_scan(const int* __restrict__ cnt, int* __restrict__ rowptr,
                       int* __restrict__ cursor) {
    __shared__ int part[256];
    const int t = threadIdx.x;
    const int i0 = t * 20, i1 = min(N_NODES, i0 + 20);
    int s = 0;
    for (int i = i0; i < i1; ++i) s += cnt[i];
    part[t] = s;
    __syncthreads();
    for (int off = 1; off < 256; off <<= 1) {
        int v = (t >= off) ? part[t - off] : 0;
        __syncthreads();
        part[t] += v;
        __syncthreads();
    }
    int run = (t > 0) ? part[t - 1] : 0;
    for (int i = i0; i < i1; ++i) { rowptr[i] = run; cursor[i] = run; run += cnt[i]; }
    if (i0 < N_NODES && i1 == N_NODES) rowptr[N_NODES] = run;
}

__global__ void k_scatter(const int* __restrict__ dst, int* __restrict__ cursor,
                          int* __restrict__ ecsr) {
    int e = blockIdx.x * 256 + threadIdx.x;
    if (e < E_EDGES) {
        int p = atomicAdd(&cursor[dst[e]], 1);
        ecsr[p] = e;
    }
}

// ---------------- shared 4x4 MFMA step (128B-row tiles) ----------------
__device__ __forceinline__ void mfma_step(const unsigned char* lA, const unsigned char* lB,
                                          int wr, int wc, int lane, f32x4 (&acc)[4][4]) {
    const int row0 = wr * 64 + (lane & 15);
    const int nrow0 = wc * 64 + (lane & 15);
    const int kslot = (lane >> 4) * 16;
#pragma unroll
    for (int ks = 0; ks < 2; ++ks) {
        short8 a[4], b[4];
#pragma unroll
        for (int m = 0; m < 4; ++m)
            a[m] = *(const short8*)(lA + SWZB(row0 + m * 16, ks * 64 + kslot));
#pragma unroll
        for (int n = 0; n < 4; ++n)
            b[n] = *(const short8*)(lB + SWZB(nrow0 + n * 16, ks * 64 + kslot));
#pragma unroll
        for (int m = 0; m < 4; ++m)
#pragma unroll
            for (int n = 0; n < 4; ++n)
                acc[m][n] = __builtin_amdgcn_mfma_f32_16x16x32_bf16(a[m], b[n], acc[m][n], 0, 0, 0);
    }
}

// ---------------- GEMM1: u = edge_t2v @ W1_top  (M=16000,K=128,N=512) ----------------
__global__ __launch_bounds__(256) void k_gemm1(const float* __restrict__ et2v,
                                               const ushort* __restrict__ W1t,
                                               ushort* __restrict__ u) {
    __shared__ __align__(16) unsigned char lds2[32768];
    unsigned char* lA = lds2;
    unsigned char* lB = lds2 + 16384;
    const int t = threadIdx.x;
    const int m0 = (blockIdx.x >> 2) * 128;
    const int n0 = (blockIdx.x & 3) * 128;
    const int lane = t & 63, wid = t >> 6, wr = wid >> 1, wc = wid & 1;
    const int srow = t >> 1, koff = (t & 1) * 32, lb0 = (t & 1) * 64;
    f32x4 acc[4][4] = {};
    for (int step = 0; step < 2; ++step) {
        const float4* ap = (const float4*)(et2v + (size_t)(m0 + srow) * 128 + step * 64 + koff);
#pragma unroll
        for (int i = 0; i < 4; ++i) {
            float4 x0 = ap[2 * i], x1 = ap[2 * i + 1];
            *(uint4*)&lA[SWZB(srow, lb0 + i * 16)] =
                make_uint4(pk2(x0.x, x0.y), pk2(x0.z, x0.w), pk2(x1.x, x1.y), pk2(x1.z, x1.w));
        }
        const uint4* bp = (const uint4*)(W1t + (size_t)(n0 + srow) * 128 + step * 64 + koff);
#pragma unroll
        for (int i = 0; i < 4; ++i) *(uint4*)&lB[SWZB(srow, lb0 + i * 16)] = bp[i];
        __syncthreads();
        mfma_step(lA, lB, wr, wc, lane, acc);
        __syncthreads();
    }
    // C-layout -> LDS (bf16) -> coalesced uint4 store
    const int rbase = wr * 64 + ((lane >> 4) << 2);
    const int cb = wc * 64 + (lane & 15);
#pragma unroll
    for (int mm = 0; mm < 4; ++mm)
#pragma unroll
        for (int i = 0; i < 4; ++i) {
            const int r = rbase + mm * 16 + i;
#pragma unroll
            for (int nn = 0; nn < 4; ++nn)
                *(ushort*)&lds2[SWZ256(r, 2 * (cb + nn * 16))] = f2bf(acc[mm][nn][i]);
        }
    __syncthreads();
    {
        const int r = t >> 1, kh = t & 1;
        ushort* up = u + (size_t)(m0 + r) * 512 + n0 + kh * 64;
#pragma unroll
        for (int q = 0; q < 8; ++q)
            *(uint4*)(up + q * 8) = *(const uint4*)&lds2[SWZ256(r, kh * 128 + q * 16)];
    }
}

// ---------------- MEGA: gemm2+gemm3+gemm4 fused, block = 128 (e,b) rows ----------------
__global__ __launch_bounds__(256, 2) void k_mega(
    const ushort* __restrict__ u, const float* __restrict__ v_b,
    const ushort* __restrict__ W2t, const float* __restrict__ b2,
    const ushort* __restrict__ W3t, const float* __restrict__ b3,
    const ushort* __restrict__ Wallt,
    const float* __restrict__ bss, const float* __restrict__ bee,
    const ushort* __restrict__ hsrc, const ushort* __restrict__ hrel,
    const int* __restrict__ edge_start, const int* __restrict__ edge_end,
    const int* __restrict__ batch_start, const int* __restrict__ batch_end,
    ushort* __restrict__ g_e) {
    __shared__ __align__(16) unsigned char lds[65536];
    __shared__ __align__(16) float bsum[1152];    // bss[a]+bee[b], 9 combos x 128
    __shared__ int selss_s[128], selee_s[128];
    __shared__ int am_s;
    const int t = threadIdx.x;
    const int m0 = blockIdx.x * 128;
    const int lane = t & 63, wid = t >> 6, wr = wid >> 1, wc = wid & 1;
    const int srow = t >> 1, koff = (t & 1) * 32, lb0 = (t & 1) * 64;
    const int l15 = lane & 15, ls4 = (lane >> 4) << 2;
    const int kslot = (lane >> 4) * 16, kslot8 = (lane >> 4) * 8;

    if (t == 0) am_s = 0;
    __syncthreads();
    if (t < 128) {
        const int gr = m0 + t, e = gr >> 3, b = gr & 7;
        const int ss = sgnk(edge_start[e], batch_start[b]);
        const int se = sgnk(edge_end[e], batch_end[b]);
        selss_s[t] = ss; selee_s[t] = se;
        atomicOr(&am_s, (1 << ss) | (8 << se));
    }
    for (int idx = t; idx < 1152; idx += 256) {
        const int combo = idx >> 7, k = idx & 127;
        bsum[idx] = bss[(combo / 3) * 128 + k] + bee[(combo % 3) * 128 + k];
    }

    // ======== phase A: h2acc = relu(u+v_b) @ W2 (K=512, N=256 in regs) ========
    unsigned char* lA = lds;           // [0,16K)
    unsigned char* lB = lds + 16384;   // [16K,48K)
    const int ae = (m0 + srow) >> 3, ab = (m0 + srow) & 7;
    f32x4 acc2[4][8] = {};
    uint4 ucur[4], unxt[4];
    {
        const ushort* ub = u + (size_t)ae * 512 + koff;
#pragma unroll
        for (int i = 0; i < 4; ++i) ucur[i] = *(const uint4*)(ub + i * 8);
    }
    for (int step = 0; step < 8; ++step) {
        const int k0 = step * 64;
        // lA: form relu(u+v_b) from prefetched regs
        const float4* vp = (const float4*)(v_b + ab * 512 + k0 + koff);
#pragma unroll
        for (int i = 0; i < 4; ++i) {
            uint4 uv = ucur[i];
            float4 va = vp[2 * i], vb4 = vp[2 * i + 1];
            unsigned r0 = pk2(fmaxf(bflo(uv.x) + va.x, 0.f), fmaxf(bfhi(uv.x) + va.y, 0.f));
            unsigned r1 = pk2(fmaxf(bflo(uv.y) + va.z, 0.f), fmaxf(bfhi(uv.y) + va.w, 0.f));
            unsigned r2 = pk2(fmaxf(bflo(uv.z) + vb4.x, 0.f), fmaxf(bfhi(uv.z) + vb4.y, 0.f));
            unsigned r3 = pk2(fmaxf(bflo(uv.w) + vb4.z, 0.f), fmaxf(bfhi(uv.w) + vb4.w, 0.f));
            *(uint4*)&lA[SWZB(srow, lb0 + i * 16)] = make_uint4(r0, r1, r2, r3);
        }
        // lB: register-staged (proven path)
        const uint4* bp = (const uint4*)(W2t + (size_t)t * 512 + k0);
#pragma unroll
        for (int i = 0; i < 8; ++i) *(uint4*)&lB[SWZB(t, i * 16)] = bp[i];
        // prefetch next step's u (issue-early; hides under the barrier/MFMA)
        if (step < 7) {
            const ushort* ub = u + (size_t)ae * 512 + (k0 + 64) + koff;
#pragma unroll
            for (int i = 0; i < 4; ++i) unxt[i] = *(const uint4*)(ub + i * 8);
        }
        __syncthreads();
        {
            const int row0 = wr * 64 + l15;
            const int nrow0 = wc * 128 + l15;
#pragma unroll
            for (int ks = 0; ks < 2; ++ks) {
                short8 a[4], b[8];
#pragma unroll
                for (int m = 0; m < 4; ++m)
                    a[m] = *(const short8*)(lA + SWZB(row0 + m * 16, ks * 64 + kslot));
#pragma unroll
                for (int n = 0; n < 8; ++n)
                    b[n] = *(const short8*)(lB + SWZB(nrow0 + n * 16, ks * 64 + kslot));
#pragma unroll
                for (int m = 0; m < 4; ++m)
#pragma unroll
                    for (int n = 0; n < 8; ++n)
                        acc2[m][n] = __builtin_amdgcn_mfma_f32_16x16x32_bf16(a[m], b[n], acc2[m][n], 0, 0, 0);
            }
        }
        __syncthreads();
#pragma unroll
        for (int i = 0; i < 4; ++i) ucur[i] = unxt[i];
    }

    // ======== h2 tile to LDS (64KB, 128 rows x 512B, swizzled) ========
    const int rb = wr * 64 + ls4;
    const int cb2 = wc * 128 + l15;
    float b2r[8];
#pragma unroll
    for (int nn = 0; nn < 8; ++nn) b2r[nn] = b2[cb2 + nn * 16];
#pragma unroll
    for (int mm = 0; mm < 4; ++mm)
#pragma unroll
        for (int i = 0; i < 4; ++i) {
            const int r = rb + mm * 16 + i;
#pragma unroll
            for (int nn = 0; nn < 8; ++nn) {
                const int k = cb2 + nn * 16;
                *(ushort*)&lds[SWZ512(r, 2 * k)] =
                    f2bf(fmaxf(acc2[mm][nn][i] + b2r[nn], 0.f));
            }
        }
    __syncthreads();

    // ======== phase B: tau = h2 @ W3t (K=256, N=128); B direct from L2 ========
    f32x4 tacc[4][4] = {};
#pragma unroll
    for (int ks = 0; ks < 8; ++ks) {
        short8 a[4], b[4];
#pragma unroll
        for (int m = 0; m < 4; ++m) {
            const int rA = wr * 64 + l15 + m * 16;
            a[m] = *(const short8*)&lds[SWZ512(rA, ks * 64 + kslot)];
        }
#pragma unroll
        for (int n = 0; n < 4; ++n) {
            const int nB = wc * 64 + l15 + n * 16;
            b[n] = *(const short8*)(W3t + nB * 256 + ks * 32 + kslot8);
        }
#pragma unroll
        for (int m = 0; m < 4; ++m)
#pragma unroll
            for (int n = 0; n < 4; ++n)
                tacc[m][n] = __builtin_amdgcn_mfma_f32_16x16x32_bf16(a[m], b[n], tacc[m][n], 0, 0, 0);
    }
    __syncthreads();   // h2 tile consumed

    // ======== tau (bf16) -> LDS [0,32K), C-layout scatter ========
    const int cb1 = wc * 64 + l15;
    float b3r[4];
#pragma unroll
    for (int nn = 0; nn < 4; ++nn) b3r[nn] = b3[cb1 + nn * 16];
#pragma unroll
    for (int mm = 0; mm < 4; ++mm)
#pragma unroll
        for (int i = 0; i < 4; ++i) {
            const int r = rb + mm * 16 + i;
#pragma unroll
            for (int nn = 0; nn < 4; ++nn) {
                const int k2 = cb1 + nn * 16;
                *(ushort*)&lds[SWZ256(r, 2 * k2)] = f2bf(tacc[mm][nn][i] + b3r[nn]);
            }
        }
    __syncthreads();

    // ======== remap: xss = tau+hsrc (in place), xee = tau+hrel -> [32K,64K) ========
    {
        const int r = t >> 1, kh = t & 1, el = r >> 3;
        const ushort* hs = hsrc + ((size_t)(m0 >> 3) + el) * 128 + kh * 64;
        const ushort* hr = hrel + ((size_t)(m0 >> 3) + el) * 128 + kh * 64;
#pragma unroll
        for (int q = 0; q < 8; ++q) {
            const int boff = SWZ256(r, kh * 128 + q * 16);
            uint4 tv = *(const uint4*)&lds[boff];
            uint4 sv = *(const uint4*)(hs + q * 8);
            uint4 rv = *(const uint4*)(hr + q * 8);
            uint4 xs, xe;
            xs.x = addpk(tv.x, sv.x); xs.y = addpk(tv.y, sv.y);
            xs.z = addpk(tv.z, sv.z); xs.w = addpk(tv.w, sv.w);
            xe.x = addpk(tv.x, rv.x); xe.y = addpk(tv.y, rv.y);
            xe.z = addpk(tv.z, rv.z); xe.w = addpk(tv.w, rv.w);
            *(uint4*)&lds[boff] = xs;
            *(uint4*)&lds[32768 + boff] = xe;
        }
    }
    __syncthreads();

    // ======== phase C: g = sum of masked chunk GEMMs (K=128 each) ========
    int sel_ss[4], sel_ee[4];
#pragma unroll
    for (int m = 0; m < 4; ++m) {
        const int rA = wr * 64 + l15 + m * 16;
        sel_ss[m] = selss_s[rA]; sel_ee[m] = selee_s[rA];
    }
    const int am = am_s;
    const short8 zero8 = {0, 0, 0, 0, 0, 0, 0, 0};
    f32x4 gacc[4][4] = {};
    for (int c = 0; c < 6; ++c) {
        if (!((am >> c) & 1)) continue;
        const int m3 = (c < 3) ? c : c - 3;
        const int xb = (c < 3) ? 0 : 32768;
#pragma unroll
        for (int ks = 0; ks < 4; ++ks) {
            short8 a[4], b[4];
#pragma unroll
            for (int m = 0; m < 4; ++m) {
                const int rA = wr * 64 + l15 + m * 16;
                short8 v = *(const short8*)&lds[xb + SWZ256(rA, ks * 64 + kslot)];
                const int sel = (c < 3) ? sel_ss[m] : sel_ee[m];
                a[m] = (sel == m3) ? v : zero8;
            }
#pragma unroll
            for (int n = 0; n < 4; ++n) {
                const int nB = wc * 64 + l15 + n * 16;
                b[n] = *(const short8*)(Wallt + (size_t)c * 16384 + nB * 128 + ks * 32 + kslot8);
            }
#pragma unroll
            for (int m = 0; m < 4; ++m)
#pragma unroll
                for (int n = 0; n < 4; ++n)
                    gacc[m][n] = __builtin_amdgcn_mfma_f32_16x16x32_bf16(a[m], b[n], gacc[m][n], 0, 0, 0);
        }
    }
    __syncthreads();   // xss/xee consumed

    // ======== gacc (bf16) -> LDS [0,32K), then coalesced bias-add store ========
#pragma unroll
    for (int mm = 0; mm < 4; ++mm)
#pragma unroll
        for (int i = 0; i < 4; ++i) {
            const int r = rb + mm * 16 + i;
#pragma unroll
            for (int nn = 0; nn < 4; ++nn) {
                const int k2 = cb1 + nn * 16;
                *(ushort*)&lds[SWZ256(r, 2 * k2)] = f2bf(gacc[mm][nn][i]);
            }
        }
    __syncthreads();
    {
        const int r = t >> 1, kh = t & 1;
        const int c9 = selss_s[r] * 3 + selee_s[r];
        const float* bp = &bsum[c9 * 128 + kh * 64];
        ushort* gp = g_e + (size_t)(m0 + r) * 128 + kh * 64;
#pragma unroll
        for (int q = 0; q < 8; ++q) {
            uint4 gv = *(const uint4*)&lds[SWZ256(r, kh * 128 + q * 16)];
            float4 f0 = *(const float4*)(bp + q * 8);
            float4 f1 = *(const float4*)(bp + q * 8 + 4);
            uint4 o;
            o.x = pk2(bflo(gv.x) + f0.x, bfhi(gv.x) + f0.y);
            o.y = pk2(bflo(gv.y) + f0.z, bfhi(gv.y) + f0.w);
            o.z = pk2(bflo(gv.z) + f1.x, bfhi(gv.z) + f1.y);
            o.w = pk2(bflo(gv.w) + f1.z, bfhi(gv.w) + f1.w);
            *(uint4*)(gp + q * 8) = o;
        }
    }
}

// ---------------- segment softmax (gather, no atomics): block = dst node ----------------
__global__ __launch_bounds__(128) void k_segsm(const int* __restrict__ rowptr,
                                               const int* __restrict__ ecsr,
                                               const float* __restrict__ wdst,
                                               const ushort* __restrict__ g_e,
                                               float* __restrict__ out) {
    const int n = blockIdx.x, d = threadIdx.x;
    const float w = wdst[n * 128 + d];
    const int s0 = rowptr[n], s1 = rowptr[n + 1];
    float m[8], z[8], S[8];
#pragma unroll
    for (int b = 0; b < 8; ++b) { m[b] = -1e30f; z[b] = 0.f; S[b] = 0.f; }
    for (int i = s0; i < s1; ++i) {
        const int e = ecsr[i];
        const ushort* gp = g_e + (size_t)e * 1024 + d;
#pragma unroll
        for (int b = 0; b < 8; ++b) {
            float g = bf2f(gp[b * 128]);
            float sc = leaky(w * g);
            float nm = fmaxf(m[b], sc);
            float sca = __expf(m[b] - nm);
            float s = __expf(sc - nm);
            z[b] = z[b] * sca + s;
            S[b] = S[b] * sca + s * g;
            m[b] = nm;
        }
    }
#pragma unroll
    for (int b = 0; b < 8; ++b) {
        float r = S[b] / (z[b] + 1e-16f);
        out[((size_t)n * 8 + b) * 128 + d] = leaky(r);
    }
}

extern "C" void kernel_launch(void* const* d_in, const int* in_sizes, int n_in,
                              void* d_out, int out_size, void* d_ws, size_t ws_size,
                              hipStream_t stream) {
    const int* src = (const int*)d_in[0];
    const int* dst = (const int*)d_in[1];
    const int* node_idx = (const int*)d_in[2];
    const int* rel = (const int*)d_in[3];
    const int* es = (const int*)d_in[4];
    const int* eend = (const int*)d_in[5];
    const int* bs = (const int*)d_in[6];
    const int* be = (const int*)d_in[7];
    const float* node_time = (const float*)d_in[8];
    const float* edge_t2v = (const float*)d_in[9];
    const float* batch_t2v = (const float*)d_in[10];
    const float* syn = (const float*)d_in[11];
    const float* diae = (const float*)d_in[12];
    const float* diaw = (const float*)d_in[13];
    const float* diab = (const float*)d_in[14];
    const float* rele = (const float*)d_in[15];
    const float* W1 = (const float*)d_in[16];
    const float* b1 = (const float*)d_in[17];
    const float* W2 = (const float*)d_in[18];
    const float* b2 = (const float*)d_in[19];
    const float* W3 = (const float*)d_in[20];
    const float* b3 = (const float*)d_in[21];
    const float* Wss = (const float*)d_in[22];
    const float* bss = (const float*)d_in[23];
    const float* Wee = (const float*)d_in[24];
    const float* bee = (const float*)d_in[25];
    const float* ai = (const float*)d_in[26];
    const float* aj = (const float*)d_in[27];

    float* ws = (float*)d_ws;
    ushort* u = (ushort*)(ws + OFF_U);
    ushort* g_e = (ushort*)(ws + OFF_G);
    float* h_n = ws + OFF_HN;
    float* wdst = ws + OFF_WDST;
    float* v_b = ws + OFF_VB;
    ushort* W1t = (ushort*)(ws + OFF_W1T);
    ushort* W2t = (ushort*)(ws + OFF_W2T);
    ushort* W3t = (ushort*)(ws + OFF_W3T);
    ushort* Wallt = (ushort*)(ws + OFF_WALLT);
    int* cnt = (int*)(ws + OFF_CNT);
    int* rowptr = (int*)(ws + OFF_ROWP);
    int* cursor = (int*)(ws + OFF_CUR);
    int* ecsr = (int*)(ws + OFF_ECSR);
    ushort* hsrc = (ushort*)(ws + OFF_HSRC);
    ushort* hrel = (ushort*)(ws + OFF_HREL);
    float* out = (float*)d_out;

    hipMemsetAsync(cnt, 0, N_NODES * sizeof(int), stream);
    k_count<<<63, 256, 0, stream>>>(dst, cnt);
    k_scan<<<1, 256, 0, stream>>>(cnt, rowptr, cursor);
    k_scatter<<<63, 256, 0, stream>>>(dst, cursor, ecsr);

    k_wprep<<<1280, 256, 0, stream>>>(W1, W2, W3, Wss, Wee, W1t, W2t, W3t, Wallt);
    k_node<<<N_NODES, 128, 0, stream>>>(node_idx, node_time, syn, diae, diaw, diab, ai, aj, h_n, wdst);
    k_vb<<<B_Q, 512, 0, stream>>>(batch_t2v, W1, b1, v_b);
    k_egather<<<E_EDGES * D_DIM / 256, 256, 0, stream>>>(src, rel, h_n, rele, hsrc, hrel);
    k_gemm1<<<500, 256, 0, stream>>>(edge_t2v, W1t, u);
    k_mega<<<1000, 256, 0, stream>>>(u, v_b, W2t, b2, W3t, b3, Wallt, bss, bee,
                                     hsrc, hrel, es, eend, bs, be, g_e);
    k_segsm<<<N_NODES, 128, 0, stream>>>(rowptr, ecsr, wdst, g_e, out);
}

// Round 12
// 325.002 us; speedup vs baseline: 1.0469x; 1.0469x over previous
//
#include <hip/hip_runtime.h>
#include <hip/hip_bf16.h>

typedef __attribute__((ext_vector_type(8))) short short8;
typedef __attribute__((ext_vector_type(4))) float f32x4;

#define N_NODES 5000
#define E_EDGES 16000
#define B_Q 8
#define D_DIM 128

// ---- ws layout (float offsets) ----
#define OFF_G     4096000      // bf16 16,384,000 (mega -> segsm)
#define OFF_HN    12288000     // f32 640,000
#define OFF_WDST  12928000     // f32 640,000
#define OFF_VB    13568000     // f32 4,096
#define OFF_W1T   13572096     // bf16 65,536
#define OFF_W2T   13604864     // bf16 131,072
#define OFF_W3T   13670400     // bf16 32,768
#define OFF_WALLT 13686784     // bf16 98,304
#define OFF_CNT   13735936     // int 5,000
#define OFF_ROWP  13740936     // int 5,001
#define OFF_CUR   13745937     // int 5,000
#define OFF_ECSR  13750937     // int 16,000
#define OFF_HSRC  13766944     // bf16 2,048,000 (16B aligned)
#define OFF_HREL  14790944     // bf16 2,048,000
// end = 15,814,944 floats = 63.3 MB

__device__ __forceinline__ float leaky(float x) { return x > 0.f ? x : 0.01f * x; }
__device__ __forceinline__ int sgnk(int a, int b) { int d = a - b; return d > 0 ? 2 : (d == 0 ? 1 : 0); }
__device__ __forceinline__ unsigned short f2bf(float f) {
    __hip_bfloat16 h = __float2bfloat16(f);
    unsigned short r; __builtin_memcpy(&r, &h, 2); return r;
}
__device__ __forceinline__ unsigned pk2(float a, float b) {
    return (unsigned)f2bf(a) | ((unsigned)f2bf(b) << 16);
}
__device__ __forceinline__ float bflo(unsigned w) { return __uint_as_float(w << 16); }
__device__ __forceinline__ float bfhi(unsigned w) { return __uint_as_float(w & 0xffff0000u); }
__device__ __forceinline__ float bf2f(unsigned short s) { return __uint_as_float(((unsigned)s) << 16); }
__device__ __forceinline__ unsigned addpk(unsigned a, unsigned b) {
    return pk2(bflo(a) + bflo(b), bfhi(a) + bfhi(b));
}

// XOR swizzles: byte ^= (row&7)<<4, row strides 128/256/512/1024 B
#define SWZB(row, lb)   (((row) << 7)  + ((lb) ^ (((row) & 7) << 4)))
#define SWZ256(row, lb) (((row) << 8)  + ((lb) ^ (((row) & 7) << 4)))
#define SWZ512(row, lb) (((row) << 9)  + ((lb) ^ (((row) & 7) << 4)))
#define SWZ1K(row, lb)  (((row) << 10) + ((lb) ^ (((row) & 7) << 4)))

// ---------------- prepA: {wprep | node | vb | count} by block range ----------------
__global__ __launch_bounds__(256) void k_prepA(
    const float* __restrict__ W1, const float* __restrict__ W2,
    const float* __restrict__ W3, const float* __restrict__ Wss,
    const float* __restrict__ Wee,
    const int* __restrict__ node_idx, const float* __restrict__ node_time,
    const float* __restrict__ syn, const float* __restrict__ diae,
    const float* __restrict__ diaw, const float* __restrict__ diab,
    const float* __restrict__ attn_i, const float* __restrict__ attn_j,
    const float* __restrict__ bt2v, const float* __restrict__ b1,
    const int* __restrict__ dst,
    ushort* __restrict__ W1t, ushort* __restrict__ W2t,
    ushort* __restrict__ W3t, ushort* __restrict__ Wallt,
    float* __restrict__ h_n, float* __restrict__ w_dst,
    float* __restrict__ v_b, int* __restrict__ cnt) {
    const int bid = blockIdx.x, t = threadIdx.x;
    if (bid < 1280) {
        int tid = bid * 256 + t;
        if (tid < 131072) {                       // W2t[n][k] = W2[k][n]
            int n = tid >> 9, k = tid & 511;
            W2t[tid] = f2bf(W2[k * 256 + n]);
        } else if (tid < 163840) {                // W3t[n][k]
            int q = tid - 131072; int n = q >> 8, k = q & 255;
            W3t[q] = f2bf(W3[k * 128 + n]);
        } else if (tid < 262144) {                // Wallt[c][n][k]
            int q = tid - 163840; int c = q >> 14, rr = q & 16383, n = rr >> 7, k = rr & 127;
            const float* Wm = (c < 3) ? Wss : Wee; int cc = (c < 3) ? c : c - 3;
            Wallt[q] = f2bf(Wm[cc * 16384 + k * 128 + n]);
        } else if (tid < 327680) {                // W1t[n][k], 512x128
            int q = tid - 262144; int n = q >> 7, k = q & 127;
            W1t[q] = f2bf(W1[k * 512 + n]);
        }
    } else if (bid < 3780) {                      // node: 2 nodes per block
        int n = (bid - 1280) * 2 + (t >> 7), d = t & 127;
        int nid = node_idx[n];
        float h = syn[nid * D_DIM + d];
        if (d >= 64) {
            int q = d - 64;
            h += diae[nid * 64 + q] * sinf(diaw[nid * 64 + q] * node_time[n] + diab[nid * 64 + q]);
        }
        h_n[n * D_DIM + d] = h;
        w_dst[n * D_DIM + d] = h * attn_i[d] * attn_j[d];
    } else if (bid < 3788) {                      // vb: 8 blocks, 2 cols/thread
        int b = bid - 3780;
#pragma unroll
        for (int jj = 0; jj < 2; ++jj) {
            int j = t + jj * 256;
            float acc = b1[j];
            for (int i = 0; i < 128; ++i)
                acc = fmaf(bt2v[b * 128 + i], W1[(128 + i) * 512 + j], acc);
            v_b[b * 512 + j] = acc;
        }
    } else {                                      // count: blocks 3788..3850
        int e = (bid - 3788) * 256 + t;
        if (e < E_EDGES) atomicAdd(&cnt[dst[e]], 1);
    }
}

// ---------------- prepB: {egather | scan(last block)} ----------------
__global__ __launch_bounds__(256) void k_prepB(
    const int* __restrict__ src, const int* __restrict__ rtyp,
    const float* __restrict__ h_n, const float* __restrict__ rel_embed,
    const int* __restrict__ cnt,
    ushort* __restrict__ hsrc, ushort* __restrict__ hrel,
    int* __restrict__ rowptr, int* __restrict__ cursor) {
    const int bid = blockIdx.x, t = threadIdx.x;
    if (bid < 8000) {
        int idx = bid * 256 + t;                  // e*128 + d
        int e = idx >> 7, d = idx & 127;
        hsrc[idx] = f2bf(h_n[src[e] * 128 + d]);
        hrel[idx] = f2bf(rel_embed[rtyp[e] * 128 + d]);
    } else {
        __shared__ int part[256];
        const int i0 = t * 20, i1 = min(N_NODES, i0 + 20);
        int s = 0;
        for (int i = i0; i < i1; ++i) s += cnt[i];
        part[t] = s;
        __syncthreads();
        for (int off = 1; off < 256; off <<= 1) {
            int v = (t >= off) ? part[t - off] : 0;
            __syncthreads();
            part[t] += v;
            __syncthreads();
        }
        int run = (t > 0) ? part[t - 1] : 0;
        for (int i = i0; i < i1; ++i) { rowptr[i] = run; cursor[i] = run; run += cnt[i]; }
        if (i0 < N_NODES && i1 == N_NODES) rowptr[N_NODES] = run;
    }
}

__global__ void k_scatter(const int* __restrict__ dst, int* __restrict__ cursor,
                          int* __restrict__ ecsr) {
    int e = blockIdx.x * 256 + threadIdx.x;
    if (e < E_EDGES) {
        int p = atomicAdd(&cursor[dst[e]], 1);
        ecsr[p] = e;
    }
}

// ---------------- MEGA: gemm1+gemm2+gemm3+gemm4 fused, block = 128 (e,b) rows ----------------
__global__ __launch_bounds__(256, 2) void k_mega(
    const float* __restrict__ et2v, const ushort* __restrict__ W1t,
    const float* __restrict__ v_b,
    const ushort* __restrict__ W2t, const float* __restrict__ b2,
    const ushort* __restrict__ W3t, const float* __restrict__ b3,
    const ushort* __restrict__ Wallt,
    const float* __restrict__ bss, const float* __restrict__ bee,
    const ushort* __restrict__ hsrc, const ushort* __restrict__ hrel,
    const int* __restrict__ edge_start, const int* __restrict__ edge_end,
    const int* __restrict__ batch_start, const int* __restrict__ batch_end,
    ushort* __restrict__ g_e) {
    __shared__ __align__(16) unsigned char lds[65536];
    __shared__ __align__(16) float bsum[1152];    // bss[a]+bee[b], 9 combos x 128
    __shared__ int selss_s[128], selee_s[128];
    __shared__ int am_s;
    const int t = threadIdx.x;
    const int m0 = blockIdx.x * 128;
    const int e0 = m0 >> 3;                        // 16 edges per block
    const int lane = t & 63, wid = t >> 6, wr = wid >> 1, wc = wid & 1;
    const int srow = t >> 1, koff = (t & 1) * 32, lb0 = (t & 1) * 64;
    const int l15 = lane & 15, ls4 = (lane >> 4) << 2;
    const int kslot = (lane >> 4) * 16, kslot8 = (lane >> 4) * 8;

    if (t == 0) am_s = 0;
    __syncthreads();
    if (t < 128) {
        const int gr = m0 + t, e = gr >> 3, b = gr & 7;
        const int ss = sgnk(edge_start[e], batch_start[b]);
        const int se = sgnk(edge_end[e], batch_end[b]);
        selss_s[t] = ss; selee_s[t] = se;
        atomicOr(&am_s, (1 << ss) | (8 << se));
    }
    for (int idx = t; idx < 1152; idx += 256) {
        const int combo = idx >> 7, k = idx & 127;
        bsum[idx] = bss[(combo / 3) * 128 + k] + bee[(combo % 3) * 128 + k];
    }

    // ======== prologue: u-tile[16][512] = et2v_tile @ W1t  -> LDS [48K,64K) ========
    {
        // stage et2v 16 rows x 128 f32 -> bf16 [16][256B] @ [0,4K)
        const int row = t >> 4, col8 = (t & 15) * 8;
        const float4* ep = (const float4*)(et2v + ((size_t)(e0 + row)) * 128 + col8);
        float4 x0 = ep[0], x1 = ep[1];
        *(uint4*)&lds[SWZ256(row, 2 * col8)] =
            make_uint4(pk2(x0.x, x0.y), pk2(x0.z, x0.w), pk2(x1.x, x1.y), pk2(x1.z, x1.w));
    }
    __syncthreads();
    {
        f32x4 acc1[8] = {};
#pragma unroll
        for (int ks = 0; ks < 4; ++ks) {           // K = 128
            short8 a = *(const short8*)&lds[SWZ256(l15, ks * 64 + kslot)];
#pragma unroll
            for (int n = 0; n < 8; ++n) {
                const int nB = wid * 128 + n * 16 + l15;
                short8 b = *(const short8*)(W1t + (size_t)nB * 128 + ks * 32 + kslot8);
                acc1[n] = __builtin_amdgcn_mfma_f32_16x16x32_bf16(a, b, acc1[n], 0, 0, 0);
            }
        }
        __syncthreads();   // et2v tile dead
#pragma unroll
        for (int n = 0; n < 8; ++n)
#pragma unroll
            for (int i = 0; i < 4; ++i) {
                const int r = (lane >> 4) * 4 + i;
                const int cc = wid * 128 + n * 16 + l15;
                *(ushort*)&lds[49152 + SWZ1K(r, 2 * cc)] = f2bf(acc1[n][i]);
            }
    }
    __syncthreads();

    // ======== phase A: h2acc = relu(u+v_b) @ W2 (K=512, N=256 in regs) ========
    unsigned char* lA = lds;           // [0,16K)
    unsigned char* lB = lds + 16384;   // [16K,48K)
    const int urow = srow >> 3, ab = (m0 + srow) & 7;
    f32x4 acc2[4][8] = {};
    for (int step = 0; step < 8; ++step) {
        const int k0 = step * 64;
        // lA: form relu(u+v_b); u from LDS u-tile
        const float4* vp = (const float4*)(v_b + ab * 512 + k0 + koff);
#pragma unroll
        for (int i = 0; i < 4; ++i) {
            uint4 uv = *(const uint4*)&lds[49152 + SWZ1K(urow, 2 * (k0 + koff) + i * 16)];
            float4 va = vp[2 * i], vb4 = vp[2 * i + 1];
            unsigned r0 = pk2(fmaxf(bflo(uv.x) + va.x, 0.f), fmaxf(bfhi(uv.x) + va.y, 0.f));
            unsigned r1 = pk2(fmaxf(bflo(uv.y) + va.z, 0.f), fmaxf(bfhi(uv.y) + va.w, 0.f));
            unsigned r2 = pk2(fmaxf(bflo(uv.z) + vb4.x, 0.f), fmaxf(bfhi(uv.z) + vb4.y, 0.f));
            unsigned r3 = pk2(fmaxf(bflo(uv.w) + vb4.z, 0.f), fmaxf(bfhi(uv.w) + vb4.w, 0.f));
            *(uint4*)&lA[SWZB(srow, lb0 + i * 16)] = make_uint4(r0, r1, r2, r3);
        }
        // lB: register-staged W2t tile
        const uint4* bp = (const uint4*)(W2t + (size_t)t * 512 + k0);
#pragma unroll
        for (int i = 0; i < 8; ++i) *(uint4*)&lB[SWZB(t, i * 16)] = bp[i];
        __syncthreads();
        {
            const int row0 = wr * 64 + l15;
            const int nrow0 = wc * 128 + l15;
#pragma unroll
            for (int ks = 0; ks < 2; ++ks) {
                short8 a[4], b[8];
#pragma unroll
                for (int m = 0; m < 4; ++m)
                    a[m] = *(const short8*)(lA + SWZB(row0 + m * 16, ks * 64 + kslot));
#pragma unroll
                for (int n = 0; n < 8; ++n)
                    b[n] = *(const short8*)(lB + SWZB(nrow0 + n * 16, ks * 64 + kslot));
#pragma unroll
                for (int m = 0; m < 4; ++m)
#pragma unroll
                    for (int n = 0; n < 8; ++n)
                        acc2[m][n] = __builtin_amdgcn_mfma_f32_16x16x32_bf16(a[m], b[n], acc2[m][n], 0, 0, 0);
            }
        }
        __syncthreads();
    }

    // ======== h2 tile to LDS (64KB, 128 rows x 512B, swizzled) ========
    const int rb = wr * 64 + ls4;
    const int cb2 = wc * 128 + l15;
    float b2r[8];
#pragma unroll
    for (int nn = 0; nn < 8; ++nn) b2r[nn] = b2[cb2 + nn * 16];
#pragma unroll
    for (int mm = 0; mm < 4; ++mm)
#pragma unroll
        for (int i = 0; i < 4; ++i) {
            const int r = rb + mm * 16 + i;
#pragma unroll
            for (int nn = 0; nn < 8; ++nn) {
                const int k = cb2 + nn * 16;
                *(ushort*)&lds[SWZ512(r, 2 * k)] =
                    f2bf(fmaxf(acc2[mm][nn][i] + b2r[nn], 0.f));
            }
        }
    __syncthreads();

    // ======== phase B: tau = h2 @ W3t (K=256, N=128); B direct from L2 ========
    f32x4 tacc[4][4] = {};
#pragma unroll
    for (int ks = 0; ks < 8; ++ks) {
        short8 a[4], b[4];
#pragma unroll
        for (int m = 0; m < 4; ++m) {
            const int rA = wr * 64 + l15 + m * 16;
            a[m] = *(const short8*)&lds[SWZ512(rA, ks * 64 + kslot)];
        }
#pragma unroll
        for (int n = 0; n < 4; ++n) {
            const int nB = wc * 64 + l15 + n * 16;
            b[n] = *(const short8*)(W3t + nB * 256 + ks * 32 + kslot8);
        }
#pragma unroll
        for (int m = 0; m < 4; ++m)
#pragma unroll
            for (int n = 0; n < 4; ++n)
                tacc[m][n] = __builtin_amdgcn_mfma_f32_16x16x32_bf16(a[m], b[n], tacc[m][n], 0, 0, 0);
    }
    __syncthreads();   // h2 tile consumed

    // ======== tau (bf16) -> LDS [0,32K), C-layout scatter ========
    const int cb1 = wc * 64 + l15;
    float b3r[4];
#pragma unroll
    for (int nn = 0; nn < 4; ++nn) b3r[nn] = b3[cb1 + nn * 16];
#pragma unroll
    for (int mm = 0; mm < 4; ++mm)
#pragma unroll
        for (int i = 0; i < 4; ++i) {
            const int r = rb + mm * 16 + i;
#pragma unroll
            for (int nn = 0; nn < 4; ++nn) {
                const int k2 = cb1 + nn * 16;
                *(ushort*)&lds[SWZ256(r, 2 * k2)] = f2bf(tacc[mm][nn][i] + b3r[nn]);
            }
        }
    __syncthreads();

    // ======== remap: xss = tau+hsrc (in place), xee = tau+hrel -> [32K,64K) ========
    {
        const int r = t >> 1, kh = t & 1, el = r >> 3;
        const ushort* hs = hsrc + ((size_t)e0 + el) * 128 + kh * 64;
        const ushort* hr = hrel + ((size_t)e0 + el) * 128 + kh * 64;
#pragma unroll
        for (int q = 0; q < 8; ++q) {
            const int boff = SWZ256(r, kh * 128 + q * 16);
            uint4 tv = *(const uint4*)&lds[boff];
            uint4 sv = *(const uint4*)(hs + q * 8);
            uint4 rv = *(const uint4*)(hr + q * 8);
            uint4 xs, xe;
            xs.x = addpk(tv.x, sv.x); xs.y = addpk(tv.y, sv.y);
            xs.z = addpk(tv.z, sv.z); xs.w = addpk(tv.w, sv.w);
            xe.x = addpk(tv.x, rv.x); xe.y = addpk(tv.y, rv.y);
            xe.z = addpk(tv.z, rv.z); xe.w = addpk(tv.w, rv.w);
            *(uint4*)&lds[boff] = xs;
            *(uint4*)&lds[32768 + boff] = xe;
        }
    }
    __syncthreads();

    // ======== phase C: g = sum of masked chunk GEMMs (K=128 each) ========
    int sel_ss[4], sel_ee[4];
#pragma unroll
    for (int m = 0; m < 4; ++m) {
        const int rA = wr * 64 + l15 + m * 16;
        sel_ss[m] = selss_s[rA]; sel_ee[m] = selee_s[rA];
    }
    const int am = am_s;
    const short8 zero8 = {0, 0, 0, 0, 0, 0, 0, 0};
    f32x4 gacc[4][4] = {};
    for (int c = 0; c < 6; ++c) {
        if (!((am >> c) & 1)) continue;
        const int m3 = (c < 3) ? c : c - 3;
        const int xb = (c < 3) ? 0 : 32768;
#pragma unroll
        for (int ks = 0; ks < 4; ++ks) {
            short8 a[4], b[4];
#pragma unroll
            for (int m = 0; m < 4; ++m) {
                const int rA = wr * 64 + l15 + m * 16;
                short8 v = *(const short8*)&lds[xb + SWZ256(rA, ks * 64 + kslot)];
                const int sel = (c < 3) ? sel_ss[m] : sel_ee[m];
                a[m] = (sel == m3) ? v : zero8;
            }
#pragma unroll
            for (int n = 0; n < 4; ++n) {
                const int nB = wc * 64 + l15 + n * 16;
                b[n] = *(const short8*)(Wallt + (size_t)c * 16384 + nB * 128 + ks * 32 + kslot8);
            }
#pragma unroll
            for (int m = 0; m < 4; ++m)
#pragma unroll
                for (int n = 0; n < 4; ++n)
                    gacc[m][n] = __builtin_amdgcn_mfma_f32_16x16x32_bf16(a[m], b[n], gacc[m][n], 0, 0, 0);
        }
    }
    __syncthreads();   // xss/xee consumed

    // ======== gacc (bf16) -> LDS [0,32K), then coalesced bias-add store ========
#pragma unroll
    for (int mm = 0; mm < 4; ++mm)
#pragma unroll
        for (int i = 0; i < 4; ++i) {
            const int r = rb + mm * 16 + i;
#pragma unroll
            for (int nn = 0; nn < 4; ++nn) {
                const int k2 = cb1 + nn * 16;
                *(ushort*)&lds[SWZ256(r, 2 * k2)] = f2bf(gacc[mm][nn][i]);
            }
        }
    __syncthreads();
    {
        const int r = t >> 1, kh = t & 1;
        const int c9 = selss_s[r] * 3 + selee_s[r];
        const float* bp = &bsum[c9 * 128 + kh * 64];
        ushort* gp = g_e + (size_t)(m0 + r) * 128 + kh * 64;
#pragma unroll
        for (int q = 0; q < 8; ++q) {
            uint4 gv = *(const uint4*)&lds[SWZ256(r, kh * 128 + q * 16)];
            float4 f0 = *(const float4*)(bp + q * 8);
            float4 f1 = *(const float4*)(bp + q * 8 + 4);
            uint4 o;
            o.x = pk2(bflo(gv.x) + f0.x, bfhi(gv.x) + f0.y);
            o.y = pk2(bflo(gv.y) + f0.z, bfhi(gv.y) + f0.w);
            o.z = pk2(bflo(gv.z) + f1.x, bfhi(gv.z) + f1.y);
            o.w = pk2(bflo(gv.w) + f1.z, bfhi(gv.w) + f1.w);
            *(uint4*)(gp + q * 8) = o;
        }
    }
}

// ---------------- segment softmax (gather, no atomics): block = dst node ----------------
__global__ __launch_bounds__(128) void k_segsm(const int* __restrict__ rowptr,
                                               const int* __restrict__ ecsr,
                                               const float* __restrict__ wdst,
                                               const ushort* __restrict__ g_e,
                                               float* __restrict__ out) {
    const int n = blockIdx.x, d = threadIdx.x;
    const float w = wdst[n * 128 + d];
    const int s0 = rowptr[n], s1 = rowptr[n + 1];
    float m[8], z[8], S[8];
#pragma unroll
    for (int b = 0; b < 8; ++b) { m[b] = -1e30f; z[b] = 0.f; S[b] = 0.f; }
    for (int i = s0; i < s1; ++i) {
        const int e = ecsr[i];
        const ushort* gp = g_e + (size_t)e * 1024 + d;
#pragma unroll
        for (int b = 0; b < 8; ++b) {
            float g = bf2f(gp[b * 128]);
            float sc = leaky(w * g);
            float nm = fmaxf(m[b], sc);
            float sca = __expf(m[b] - nm);
            float s = __expf(sc - nm);
            z[b] = z[b] * sca + s;
            S[b] = S[b] * sca + s * g;
            m[b] = nm;
        }
    }
#pragma unroll
    for (int b = 0; b < 8; ++b) {
        float r = S[b] / (z[b] + 1e-16f);
        out[((size_t)n * 8 + b) * 128 + d] = leaky(r);
    }
}

extern "C" void kernel_launch(void* const* d_in, const int* in_sizes, int n_in,
                              void* d_out, int out_size, void* d_ws, size_t ws_size,
                              hipStream_t stream) {
    const int* src = (const int*)d_in[0];
    const int* dst = (const int*)d_in[1];
    const int* node_idx = (const int*)d_in[2];
    const int* rel = (const int*)d_in[3];
    const int* es = (const int*)d_in[4];
    const int* eend = (const int*)d_in[5];
    const int* bs = (const int*)d_in[6];
    const int* be = (const int*)d_in[7];
    const float* node_time = (const float*)d_in[8];
    const float* edge_t2v = (const float*)d_in[9];
    const float* batch_t2v = (const float*)d_in[10];
    const float* syn = (const float*)d_in[11];
    const float* diae = (const float*)d_in[12];
    const float* diaw = (const float*)d_in[13];
    const float* diab = (const float*)d_in[14];
    const float* rele = (const float*)d_in[15];
    const float* W1 = (const float*)d_in[16];
    const float* b1 = (const float*)d_in[17];
    const float* W2 = (const float*)d_in[18];
    const float* b2 = (const float*)d_in[19];
    const float* W3 = (const float*)d_in[20];
    const float* b3 = (const float*)d_in[21];
    const float* Wss = (const float*)d_in[22];
    const float* bss = (const float*)d_in[23];
    const float* Wee = (const float*)d_in[24];
    const float* bee = (const float*)d_in[25];
    const float* ai = (const float*)d_in[26];
    const float* aj = (const float*)d_in[27];

    float* ws = (float*)d_ws;
    ushort* g_e = (ushort*)(ws + OFF_G);
    float* h_n = ws + OFF_HN;
    float* wdst = ws + OFF_WDST;
    float* v_b = ws + OFF_VB;
    ushort* W1t = (ushort*)(ws + OFF_W1T);
    ushort* W2t = (ushort*)(ws + OFF_W2T);
    ushort* W3t = (ushort*)(ws + OFF_W3T);
    ushort* Wallt = (ushort*)(ws + OFF_WALLT);
    int* cnt = (int*)(ws + OFF_CNT);
    int* rowptr = (int*)(ws + OFF_ROWP);
    int* cursor = (int*)(ws + OFF_CUR);
    int* ecsr = (int*)(ws + OFF_ECSR);
    ushort* hsrc = (ushort*)(ws + OFF_HSRC);
    ushort* hrel = (ushort*)(ws + OFF_HREL);
    float* out = (float*)d_out;

    hipMemsetAsync(cnt, 0, N_NODES * sizeof(int), stream);
    k_prepA<<<3851, 256, 0, stream>>>(W1, W2, W3, Wss, Wee,
                                      node_idx, node_time, syn, diae, diaw, diab, ai, aj,
                                      batch_t2v, b1, dst,
                                      W1t, W2t, W3t, Wallt, h_n, wdst, v_b, cnt);
    k_prepB<<<8001, 256, 0, stream>>>(src, rel, h_n, rele, cnt, hsrc, hrel, rowptr, cursor);
    k_scatter<<<63, 256, 0, stream>>>(dst, cursor, ecsr);
    k_mega<<<1000, 256, 0, stream>>>(edge_t2v, W1t, v_b, W2t, b2, W3t, b3, Wallt, bss, bee,
                                     hsrc, hrel, es, eend, bs, be, g_e);
    k_segsm<<<N_NODES, 128, 0, stream>>>(rowptr, ecsr, wdst, g_e, out);
}